// Round 5
// baseline (588.232 us; speedup 1.0000x reference)
//
#include <hip/hip_runtime.h>
#include <hip/hip_bf16.h>
#include <stdint.h>

#define TOKENS 8192
#define DIN 4096
#define DOUT 4096
#define RNK 16
#define LORA_SCALE 2.0f

typedef __attribute__((ext_vector_type(8))) __bf16 bf16x8;
typedef __attribute__((ext_vector_type(4))) float f32x4;

__device__ __forceinline__ unsigned short f2bf(float f) {
    union { float f; unsigned int u; } v; v.f = f;
    unsigned int u = v.u;
    unsigned int r = (u + 0x7fffu + ((u >> 16) & 1u)) >> 16;  // RNE
    return (unsigned short)r;
}

__device__ __forceinline__ void async_copy16(const void* g, void* l) {
    __builtin_amdgcn_global_load_lds(
        (const __attribute__((address_space(1))) void*)g,
        (__attribute__((address_space(3))) void*)l,
        16, 0, 0);
}

// ---------------- kernel 1: cast x (fp32) -> bf16, grid-stride ----------------
__global__ void cast_x_kernel(const float4* __restrict__ x, ushort4* __restrict__ xb) {
    const int total = TOKENS * DIN / 4;
    for (int i = blockIdx.x * blockDim.x + threadIdx.x; i < total;
         i += gridDim.x * blockDim.x) {
        float4 v = x[i];
        ushort4 o;
        o.x = f2bf(v.x); o.y = f2bf(v.y); o.z = f2bf(v.z); o.w = f2bf(v.w);
        xb[i] = o;
    }
}

// ---------------- kernel 2: W' = bf16(W + 2 * B @ A) ----------------
__global__ void fold_w_kernel(const float* __restrict__ W,
                              const float* __restrict__ lA,
                              const float* __restrict__ lB,
                              ushort* __restrict__ Wb) {
    int o  = blockIdx.y;
    int i0 = (blockIdx.x * blockDim.x + threadIdx.x) * 4;
    __shared__ float sB[RNK];
    if (threadIdx.x < RNK) sB[threadIdx.x] = lB[(size_t)o * RNK + threadIdx.x];
    __syncthreads();
    float4 w = *(const float4*)(W + (size_t)o * DIN + i0);
    float ax = 0.f, ay = 0.f, az = 0.f, aw = 0.f;
#pragma unroll
    for (int r = 0; r < RNK; r++) {
        float4 a = *(const float4*)(lA + (size_t)r * DIN + i0);
        float b = sB[r];
        ax += b * a.x; ay += b * a.y; az += b * a.z; aw += b * a.w;
    }
    ushort4 outv;
    outv.x = f2bf(w.x + LORA_SCALE * ax);
    outv.y = f2bf(w.y + LORA_SCALE * ay);
    outv.z = f2bf(w.z + LORA_SCALE * az);
    outv.w = f2bf(w.w + LORA_SCALE * aw);
    *(ushort4*)(Wb + (size_t)o * DIN + i0) = outv;
}

// ---------------- kernel 3: Y = Xb @ Wb^T + bias ----------------
// 2-blocks-per-CU design (m114 overlap engine): BM=256 x BN=128, 4 waves
// (2x2 grid of 128x64 per-wave tiles), BK=32, ring-3 LDS = 72 KiB/block ->
// 2 blocks/CU (144 <= 160 KiB); ~200 VGPR <= 256 -> 8 waves/CU. Each SIMD
// hosts one wave from EACH block: independent barrier groups, so one block's
// ds_read burst overlaps the other's MFMA cluster via hardware arbitration
// (m114) -- the overlap that barrier-locked single-block schedules can't get.
// Loose m97-family loop: stage t+2 (6 gload_lds/thread), 12 ds_read_b128,
// 32 MFMA (compiler interleaves with counted lgkmcnt, m97 asm evidence),
// one boundary vmcnt(6)+barrier per tile (never 0 mid-loop).
//
// Ring-3 safety (1 barrier/tile): region t writes slot (t+2)%3, whose readers
// (tile t-1) finished before the boundary barrier of region t-1. Reads of
// slot t%3 (staged in region t-2) landed by boundary vmcnt(6) of region t-1
// (outstanding there = only tile t+1's 6 newest loads; FIFO, m135).
//
// LDS rows are 64 B (32 bf16) = half the 128-B bank period. Swizzle: chunk
// (16 B) for (row r, k-chunk q) at position p = q ^ ((r>>1)&3). Per b128
// read, (r&1) splits lanes across the two 64-B halves and p spreads each
// 8-lane group over all 4 chunk slots 2x -> 2-way aliasing = free (m136).
// global_load_lds writes linearly, so the inverse permutation is applied to
// the per-lane GLOBAL source address (m173).
#define BM 256
#define BN 128
#define BK 32
#define NT (DIN / BK)            // 128 K-tiles
#define SLOT_U16 12288           // A 8192 + B 4096 ushorts = 24 KiB
#define SLOT_BYTES 24576
#define B_OFF_BYTES 16384

__global__ __launch_bounds__(256, 2) void gemm_bias_kernel(
    const ushort* __restrict__ Xb, const ushort* __restrict__ Wb,
    const float* __restrict__ bias, float* __restrict__ Y) {

    __shared__ ushort smem[3 * SLOT_U16];   // 72 KiB ring

    const int tid  = threadIdx.x;
    const int lane = tid & 63;
    const int wave = tid >> 6;

    // XCD-bijective swizzle: 1024 wgs, 8 XCDs, 128 contiguous tiles per XCD.
    const int bid  = blockIdx.x;
    const int sbid = (bid & 7) * 128 + (bid >> 3);
    const int m0 = (sbid >> 5) * BM;        // 32 M-tiles
    const int n0 = (sbid & 31) * BN;        // 32 N-tiles

    const int wm = (wave >> 1) * 128;       // per-wave 128x64 output
    const int wn = (wave & 1) * 64;

    // ---- staging sources (inverse-swizzled): thread t covers chunk t+256j.
    // chunk ci: row L=ci>>2, pos p=ci&3, global chunk g=p^((L>>1)&3).
    // +256 chunks = +64 rows -> same g (64/2 = 32 = 0 mod 4).
    const int rowS = tid >> 2;
    const int gS   = (tid & 3) ^ ((rowS >> 1) & 3);
    const ushort* pA = Xb + (size_t)(m0 + rowS) * DIN + gS * 8;
    const ushort* pB = Wb + (size_t)(n0 + rowS) * DIN + gS * 8;

#define STAGE(slot, t_) do { \
        const size_t ko_ = (size_t)(t_) * BK; \
        ushort* dA_ = smem + (slot) * SLOT_U16 + tid * 8; \
        const ushort* sA_ = pA + ko_; \
        async_copy16(sA_,                    dA_); \
        async_copy16(sA_ +  64 * (size_t)DIN, dA_ + 2048); \
        async_copy16(sA_ + 128 * (size_t)DIN, dA_ + 4096); \
        async_copy16(sA_ + 192 * (size_t)DIN, dA_ + 6144); \
        ushort* dB_ = smem + (slot) * SLOT_U16 + 8192 + tid * 8; \
        const ushort* sB_ = pB + ko_; \
        async_copy16(sB_,                    dB_); \
        async_copy16(sB_ +  64 * (size_t)DIN, dB_ + 2048); \
    } while (0)

    // ---- fragment-read byte offsets (swizzle-aware, constant per lane) ----
    // frag row = (wm|wn) + 16*f + lr; g = q ^ ((lr>>1)&3)  (wm/2, wn/2 = 0 mod 4)
    const int lr = lane & 15, q = lane >> 4;
    const int gF = q ^ ((lr >> 1) & 3);
    const int offA = (wm + lr) * 64 + gF * 16;
    const int offB = B_OFF_BYTES + (wn + lr) * 64 + gF * 16;
    const char* smemc = (const char*)smem;

    f32x4 acc[8][4] = {};

    // ---- prologue: stage tiles 0,1; wait tile 0 landed (tile 1 in flight) ----
    STAGE(0, 0);
    STAGE(1, 1);
    asm volatile("s_waitcnt vmcnt(6)" ::: "memory");
    __builtin_amdgcn_s_barrier();

    int s = 0, s2 = 2;   // slot of tile t, slot of tile t+2
#pragma unroll 1
    for (int t = 0; t < NT; ++t) {
        if (t + 2 < NT) STAGE(s2, t + 2);

        const char* base = smemc + s * SLOT_BYTES;
        bf16x8 af[8], bf[4];
#pragma unroll
        for (int m = 0; m < 8; m++) af[m] = *(const bf16x8*)(base + offA + 1024 * m);
#pragma unroll
        for (int n = 0; n < 4; n++) bf[n] = *(const bf16x8*)(base + offB + 1024 * n);

#pragma unroll
        for (int m = 0; m < 8; m++)
#pragma unroll
            for (int n = 0; n < 4; n++)
                acc[m][n] = __builtin_amdgcn_mfma_f32_16x16x32_bf16(
                    af[m], bf[n], acc[m][n], 0, 0, 0);

        // boundary: counted vmcnt + one barrier per tile
        if (t < NT - 2) {
            asm volatile("s_waitcnt vmcnt(6)" ::: "memory");
            __builtin_amdgcn_s_barrier();
        } else if (t == NT - 2) {
            asm volatile("s_waitcnt vmcnt(0)" ::: "memory");
            __builtin_amdgcn_s_barrier();
        }
        s  = (s  == 2) ? 0 : s  + 1;
        s2 = (s2 == 2) ? 0 : s2 + 1;
    }

    // ---- epilogue: C/D layout col=lane&15, row=(lane>>4)*4+reg [m89/m91] ----
    const int col  = lane & 15;
    const int qrow = (lane >> 4) * 4;
#pragma unroll
    for (int n = 0; n < 4; n++) {
        const int nn = n0 + wn + n * 16 + col;
        const float bv = bias[nn];
#pragma unroll
        for (int m = 0; m < 8; m++) {
            const int mm = m0 + wm + m * 16 + qrow;
            float* yp = Y + (size_t)mm * DOUT + nn;
            yp[0]                = acc[m][n].x + bv;
            yp[(size_t)DOUT]     = acc[m][n].y + bv;
            yp[2 * (size_t)DOUT] = acc[m][n].z + bv;
            yp[3 * (size_t)DOUT] = acc[m][n].w + bv;
        }
    }
#undef STAGE
}

extern "C" void kernel_launch(void* const* d_in, const int* in_sizes, int n_in,
                              void* d_out, int out_size, void* d_ws, size_t ws_size,
                              hipStream_t stream) {
    const float* x    = (const float*)d_in[0];
    const float* W    = (const float*)d_in[1];
    const float* bias = (const float*)d_in[2];
    const float* lA   = (const float*)d_in[3];
    const float* lB   = (const float*)d_in[4];
    float* Y = (float*)d_out;

    ushort* xb = (ushort*)d_ws;                       // 64 MB
    ushort* wb = xb + (size_t)TOKENS * DIN;           // +32 MB

    cast_x_kernel<<<2048, 256, 0, stream>>>((const float4*)x, (ushort4*)xb);
    fold_w_kernel<<<dim3(DIN / (256 * 4), DOUT), 256, 0, stream>>>(W, lA, lB, wb);
    gemm_bias_kernel<<<dim3((TOKENS / BM) * (DOUT / BN)), 256, 0, stream>>>(
        xb, wb, bias, Y);
}